// Round 8
// baseline (181.138 us; speedup 1.0000x reference)
//
#include <hip/hip_runtime.h>
#include <math.h>

#define SCALING 0.125f

typedef __attribute__((ext_vector_type(8))) short short8;
typedef __attribute__((ext_vector_type(4))) float f32x4;

// round-to-nearest-even fp32 -> bf16
static __device__ __forceinline__ unsigned short bf16r(float x) {
  unsigned int u = __float_as_uint(x);
  u += 0x7fffu + ((u >> 16) & 1u);
  return (unsigned short)(u >> 16);
}
static __device__ __forceinline__ float bf16f(unsigned short h) {
  return __uint_as_float(((unsigned int)h) << 16);
}
// pack two fp32 -> bf16x2 via v_perm_b32 merge
static __device__ __forceinline__ unsigned int pk_bf16(float lo, float hi) {
  unsigned int ua = __float_as_uint(lo);
  unsigned int ub = __float_as_uint(hi);
  ua += 0x7fffu + ((ua >> 16) & 1u);
  ub += 0x7fffu + ((ub >> 16) & 1u);
  return __builtin_amdgcn_perm(ub, ua, 0x07060302u);
}
// fp32x4 -> bf16 hi + residual lo
static __device__ __forceinline__ void split4(float4 x, ushort4& h, ushort4& l) {
  h.x = bf16r(x.x); l.x = bf16r(x.x - bf16f(h.x));
  h.y = bf16r(x.y); l.y = bf16r(x.y - bf16f(h.y));
  h.z = bf16r(x.z); l.z = bf16r(x.z - bf16f(h.z));
  h.w = bf16r(x.w); l.w = bf16r(x.w - bf16f(h.w));
}
union U4S8 { uint4 u; short8 s; };

// ---------------------------------------------------------------------------
// Kernel P: one-shot hi/lo bf16 split of all loop-invariant GEMM operands.
// R3-verbatim.
// ---------------------------------------------------------------------------
__global__ __launch_bounds__(256)
void prep_kernel(const float* __restrict__ query,
                 const float* __restrict__ key,
                 const float* __restrict__ value,
                 const float* __restrict__ W,
                 const float* __restrict__ out_w,
                 unsigned short* __restrict__ Xh,
                 unsigned short* __restrict__ Xl,
                 unsigned short* __restrict__ Wh,
                 unsigned short* __restrict__ Wl,
                 unsigned short* __restrict__ Owh,
                 unsigned short* __restrict__ Owl) {
  const int t = blockIdx.x * 256 + threadIdx.x;  // 0..655359
  const int e = t * 4;
  const float* __restrict__ src;
  unsigned short *dh, *dl;
  if (e < 1572864) {               // query|key|value: 3 x 524288 floats
    const int g = e >> 19, j = e & 524287;
    src = (g == 0 ? query : g == 1 ? key : value) + j;
    dh = Xh + e; dl = Xl + e;
  } else if (e < 2359296) {        // W: 1536x512
    const int j = e - 1572864;
    src = W + j; dh = Wh + j; dl = Wl + j;
  } else {                         // out_w: 512x512
    const int j = e - 2359296;
    src = out_w + j; dh = Owh + j; dl = Owl + j;
  }
  const float4 v = *(const float4*)src;
  ushort4 hh, ll;
  split4(v, hh, ll);
  *(ushort4*)dh = hh;
  *(ushort4*)dl = ll;
}

// ---------------------------------------------------------------------------
// Kernel A v5: R7-verbatim (BK=64, 64m x 32n, 768 blocks; measured neutral
// vs R3, kept as marginal best).
// ---------------------------------------------------------------------------
__global__ __launch_bounds__(256)
void projmm_kernel(const unsigned short* __restrict__ Xh,
                   const unsigned short* __restrict__ Xl,
                   const unsigned short* __restrict__ Wh,
                   const unsigned short* __restrict__ Wl,
                   const float* __restrict__ bias,
                   float* __restrict__ qh, float* __restrict__ kh,
                   unsigned short* __restrict__ vh) {
  __shared__ __align__(16) unsigned short Ah[64 * 72];
  __shared__ __align__(16) unsigned short Al[64 * 72];
  __shared__ __align__(16) unsigned short Bh[32 * 72];
  __shared__ __align__(16) unsigned short Bl[32 * 72];
  const int n0 = blockIdx.x * 32;  // 0..1504
  const int g = n0 >> 9;           // 0=q,1=k,2=v (32-tiles never straddle 512)
  const unsigned short* __restrict__ Xgh = Xh + g * 524288;
  const unsigned short* __restrict__ Xgl = Xl + g * 524288;
  const int m0 = blockIdx.y * 64;
  const int tid = threadIdx.x;
  const int w = tid >> 6, lane = tid & 63;
  const int quad = lane >> 4, n15 = lane & 15;
  const int srow = tid >> 2;        // 0..63 (A rows)
  const int scol = (tid & 3) * 16;  // 0,16,32,48 (ushort cols)
  const bool doB = tid >= 128;
  const int brow = (tid & 127) >> 2;   // 0..31 (B rows, waves 2-3)
  const int bcol = (tid & 3) * 16;

  f32x4 acc[2];
#pragma unroll
  for (int nt = 0; nt < 2; ++nt) acc[nt] = (f32x4){0.f, 0.f, 0.f, 0.f};

  uint4 rah0, rah1, ral0, ral1, rbh0, rbh1, rbl0, rbl1;
  {
    const int ar = (m0 + srow) * 512 + scol;
    rah0 = *(const uint4*)&Xgh[ar];   rah1 = *(const uint4*)&Xgh[ar + 8];
    ral0 = *(const uint4*)&Xgl[ar];   ral1 = *(const uint4*)&Xgl[ar + 8];
  }
  if (doB) {
    const int br = (n0 + brow) * 512 + bcol;
    rbh0 = *(const uint4*)&Wh[br];    rbh1 = *(const uint4*)&Wh[br + 8];
    rbl0 = *(const uint4*)&Wl[br];    rbl1 = *(const uint4*)&Wl[br + 8];
  }

  for (int k0 = 0; k0 < 512; k0 += 64) {
    __syncthreads();
    *(uint4*)&Ah[srow * 72 + scol] = rah0; *(uint4*)&Ah[srow * 72 + scol + 8] = rah1;
    *(uint4*)&Al[srow * 72 + scol] = ral0; *(uint4*)&Al[srow * 72 + scol + 8] = ral1;
    if (doB) {
      *(uint4*)&Bh[brow * 72 + bcol] = rbh0; *(uint4*)&Bh[brow * 72 + bcol + 8] = rbh1;
      *(uint4*)&Bl[brow * 72 + bcol] = rbl0; *(uint4*)&Bl[brow * 72 + bcol + 8] = rbl1;
    }
    __syncthreads();
    if (k0 + 64 < 512) {
      const int ar = (m0 + srow) * 512 + k0 + 64 + scol;
      rah0 = *(const uint4*)&Xgh[ar]; rah1 = *(const uint4*)&Xgh[ar + 8];
      ral0 = *(const uint4*)&Xgl[ar]; ral1 = *(const uint4*)&Xgl[ar + 8];
      if (doB) {
        const int br = (n0 + brow) * 512 + k0 + 64 + bcol;
        rbh0 = *(const uint4*)&Wh[br]; rbh1 = *(const uint4*)&Wh[br + 8];
        rbl0 = *(const uint4*)&Wl[br]; rbl1 = *(const uint4*)&Wl[br + 8];
      }
    }
#pragma unroll
    for (int kk = 0; kk < 2; ++kk) {
      short8 ah = *(const short8*)&Ah[(w * 16 + n15) * 72 + kk * 32 + quad * 8];
      short8 al = *(const short8*)&Al[(w * 16 + n15) * 72 + kk * 32 + quad * 8];
#pragma unroll
      for (int nt = 0; nt < 2; ++nt) {
        short8 bh = *(const short8*)&Bh[(nt * 16 + n15) * 72 + kk * 32 + quad * 8];
        short8 bl = *(const short8*)&Bl[(nt * 16 + n15) * 72 + kk * 32 + quad * 8];
        acc[nt] = __builtin_amdgcn_mfma_f32_16x16x32_bf16(ah, bh, acc[nt], 0, 0, 0);
        acc[nt] = __builtin_amdgcn_mfma_f32_16x16x32_bf16(ah, bl, acc[nt], 0, 0, 0);
        acc[nt] = __builtin_amdgcn_mfma_f32_16x16x32_bf16(al, bh, acc[nt], 0, 0, 0);
      }
    }
  }

#pragma unroll
  for (int nt = 0; nt < 2; ++nt) {
    const int j = n0 + nt * 16 + n15;
    const int jj = j & 511;
    const int head = jj >> 6;
    const int hd = jj & 63;
    const float bj = bias[j];
#pragma unroll
    for (int r = 0; r < 4; ++r) {
      const int row = m0 + w * 16 + quad * 4 + r;
      const int t = row >> 3;
      const int batch = row & 7;
      const int i = batch * 8 + head;
      const int idx = ((i << 7) + t) * 64 + hd;
      const float val = acc[nt][r] + bj;
      if (g == 0)      qh[idx] = val * SCALING;
      else if (g == 1) kh[idx] = val;
      else             vh[idx] = bf16r(val);
    }
  }
}

// ---------------------------------------------------------------------------
// Kernel B v4: R3 structure with ONE change — bias fed as MFMA C-operand
// (R1-verified: passed with absmax exactly 0.0001220703). Removes the 64
// acc zero-inits and 64 bias adds per head per thread (~10% of the VALU
// stream, on the per-head critical path). Max-reduce association unchanged
// in value (max is exactly associative). All staging/barriers identical.
// ---------------------------------------------------------------------------
__global__ __launch_bounds__(256, 2)
void score_kernel(const float* __restrict__ qh,
                  const float* __restrict__ kh,
                  const unsigned short* __restrict__ vh,
                  const float* __restrict__ cbias,
                  unsigned short* __restrict__ attn_h,
                  unsigned short* __restrict__ attn_l) {
  __shared__ __align__(16) unsigned short Ks[2][128 * 72];
  __shared__ __align__(16) unsigned short Vs[2][128 * 72];
  __shared__ float rowS[8 * 128];  // fused rows, then softmax weights

  const int ab = blockIdx.x;  // batch*128 + a
  const int batch = ab >> 7;
  const int a = ab & 127;
  const int tid = threadIdx.x;
  const int w = tid >> 6;
  const int lane = tid & 63;
  const int quad = lane >> 4;
  const int n15 = lane & 15;
  const int col8 = (tid & 7) * 8;

  // bias fragment preload (head-invariant coords; verified mapping)
  const float* __restrict__ bp = cbias + (size_t)ab * 16384;
  f32x4 biasReg[8][2];
#pragma unroll
  for (int ic = 0; ic < 8; ++ic)
#pragma unroll
    for (int jb = 0; jb < 2; ++jb) {
      const int b = w * 32 + jb * 16 + n15;
      biasReg[ic][jb] = *(const f32x4*)&bp[b * 128 + ic * 16 + quad * 4];
    }

  // ---- prologue: stage head 0 into buffer 0 ----
  {
    const int i = batch * 8;
    const float* __restrict__ kb = kh + (size_t)i * 8192;
    const uint4* __restrict__ vb4 = (const uint4*)(vh + (size_t)i * 8192);
    const float* __restrict__ qa = qh + ((size_t)i * 128 + a) * 64;
    f32x4 q0 = *(const f32x4*)&qa[col8];
    f32x4 q1 = *(const f32x4*)&qa[col8 + 4];
#pragma unroll
    for (int j = 0; j < 4; ++j) {
      const int gg = j * 256 + tid;
      const int row = gg >> 3;
      *(uint4*)&Vs[0][row * 72 + col8] = vb4[gg];
      f32x4 k0 = *(const f32x4*)&kb[8 * gg];
      f32x4 k1 = *(const f32x4*)&kb[8 * gg + 4];
      k0 *= q0;
      k1 *= q1;
      uint4 pk;
      pk.x = pk_bf16(k0[0], k0[1]); pk.y = pk_bf16(k0[2], k0[3]);
      pk.z = pk_bf16(k1[0], k1[1]); pk.w = pk_bf16(k1[2], k1[3]);
      *(uint4*)&Ks[0][row * 72 + col8] = pk;
    }
  }
  __syncthreads();

  for (int h = 0; h < 8; ++h) {
    const int buf = h & 1;
    const int i = batch * 8 + h;

    // ---- issue next head's global loads (in flight during MFMA)
    uint4 vreg[4];
    f32x4 kreg[4][2];
    f32x4 qn0, qn1;
    if (h < 7) {
      const int in = i + 1;
      const float* __restrict__ kb = kh + (size_t)in * 8192;
      const uint4* __restrict__ vb4 = (const uint4*)(vh + (size_t)in * 8192);
      const float* __restrict__ qa = qh + ((size_t)in * 128 + a) * 64;
      qn0 = *(const f32x4*)&qa[col8];
      qn1 = *(const f32x4*)&qa[col8 + 4];
#pragma unroll
      for (int j = 0; j < 4; ++j) {
        const int gg = j * 256 + tid;
        vreg[j] = vb4[gg];
        kreg[j][0] = *(const f32x4*)&kb[8 * gg];
        kreg[j][1] = *(const f32x4*)&kb[8 * gg + 4];
      }
    }

    // ---- B-fragments from Ks[buf]
    short8 bf[2][2];
#pragma unroll
    for (int jb = 0; jb < 2; ++jb)
#pragma unroll
      for (int kk = 0; kk < 2; ++kk)
        bf[jb][kk] = *(const short8*)&Ks[buf][(w * 32 + jb * 16 + n15) * 72 +
                                             kk * 32 + quad * 8];

    // ---- MFMA: S^T[c,b]; bias as C-init (R1-verified, frees 128 VALU/tile-set)
    f32x4 acc[8][2];
#pragma unroll
    for (int ic = 0; ic < 8; ++ic) {
      short8 a0 = *(const short8*)&Vs[buf][(ic * 16 + n15) * 72 + quad * 8];
      short8 a1 = *(const short8*)&Vs[buf][(ic * 16 + n15) * 72 + 32 + quad * 8];
      acc[ic][0] = __builtin_amdgcn_mfma_f32_16x16x32_bf16(a0, bf[0][0], biasReg[ic][0], 0, 0, 0);
      acc[ic][0] = __builtin_amdgcn_mfma_f32_16x16x32_bf16(a1, bf[0][1], acc[ic][0], 0, 0, 0);
      acc[ic][1] = __builtin_amdgcn_mfma_f32_16x16x32_bf16(a0, bf[1][0], biasReg[ic][1], 0, 0, 0);
      acc[ic][1] = __builtin_amdgcn_mfma_f32_16x16x32_bf16(a1, bf[1][1], acc[ic][1], 0, 0, 0);
    }

    // ---- pack + store next head's staging into the other buffer
    if (h < 7) {
      const int nb = buf ^ 1;
#pragma unroll
      for (int j = 0; j < 4; ++j) {
        const int gg = j * 256 + tid;
        const int row = gg >> 3;
        *(uint4*)&Vs[nb][row * 72 + col8] = vreg[j];
        kreg[j][0] *= qn0;
        kreg[j][1] *= qn1;
        uint4 pk;
        pk.x = pk_bf16(kreg[j][0][0], kreg[j][0][1]);
        pk.y = pk_bf16(kreg[j][0][2], kreg[j][0][3]);
        pk.z = pk_bf16(kreg[j][1][0], kreg[j][1][1]);
        pk.w = pk_bf16(kreg[j][1][2], kreg[j][1][3]);
        *(uint4*)&Ks[nb][row * 72 + col8] = pk;
      }
    }

    // ---- epilogue: mean/max over c (bias already in acc) -> rowS (LDS)
    float fsum[2] = {0.f, 0.f};
    float fmx[2] = {-INFINITY, -INFINITY};
#pragma unroll
    for (int ic = 0; ic < 8; ++ic)
#pragma unroll
      for (int jb = 0; jb < 2; ++jb) {
        const float v0 = acc[ic][jb][0];
        const float v1 = acc[ic][jb][1];
        const float v2 = acc[ic][jb][2];
        const float v3 = acc[ic][jb][3];
        fsum[jb] += (v0 + v1) + (v2 + v3);
        fmx[jb] = fmaxf(fmx[jb], fmaxf(fmaxf(v0, v1), fmaxf(v2, v3)));
      }
#pragma unroll
    for (int off = 16; off <= 32; off <<= 1) {
#pragma unroll
      for (int jb = 0; jb < 2; ++jb) {
        fsum[jb] += __shfl_xor(fsum[jb], off, 64);
        fmx[jb] = fmaxf(fmx[jb], __shfl_xor(fmx[jb], off, 64));
      }
    }
    if (quad == 0) {
      rowS[h * 128 + w * 32 + n15] = fsum[0] * (1.0f / 128.0f) + fmx[0];
      rowS[h * 128 + w * 32 + 16 + n15] = fsum[1] * (1.0f / 128.0f) + fmx[1];
    }

    __syncthreads();  // h's reads done; h's stores visible; rowS visible
  }

  // ---- fused tail: softmax over b + attn bmm; wave w handles heads 2w,2w+1
#pragma unroll
  for (int hh = 0; hh < 2; ++hh) {
    const int h = w * 2 + hh;
    const int i = batch * 8 + h;
    float f0 = rowS[h * 128 + lane], f1 = rowS[h * 128 + 64 + lane];
    float m = fmaxf(f0, f1);
#pragma unroll
    for (int off = 32; off >= 1; off >>= 1) m = fmaxf(m, __shfl_xor(m, off, 64));
    const float e0 = expf(f0 - m), e1 = expf(f1 - m);
    float s = e0 + e1;
#pragma unroll
    for (int off = 32; off >= 1; off >>= 1) s += __shfl_xor(s, off, 64);
    const float inv = 1.0f / s;
    rowS[h * 128 + lane] = e0 * inv;       // same wave produces & consumes:
    rowS[h * 128 + 64 + lane] = e1 * inv;  // no barrier needed
    const float* __restrict__ qp = qh + (size_t)i * 8192 + lane;
    float acc2 = 0.0f;
#pragma unroll 8
    for (int b = 0; b < 128; ++b)
      acc2 = fmaf(rowS[h * 128 + b], qp[b * 64], acc2);
    const size_t idx = ((size_t)a * 8 + batch) * 512 + h * 64 + lane;
    const unsigned short hi = bf16r(acc2);
    attn_h[idx] = hi;
    attn_l[idx] = bf16r(acc2 - bf16f(hi));
  }
}

// ---------------------------------------------------------------------------
// Kernel D: output projection, R3-verbatim (BK=64, 64m x 32n, 256 blocks).
// ---------------------------------------------------------------------------
__global__ __launch_bounds__(256)
void outmm_kernel(const unsigned short* __restrict__ Xah,
                  const unsigned short* __restrict__ Xal,
                  const unsigned short* __restrict__ Owh,
                  const unsigned short* __restrict__ Owl,
                  const float* __restrict__ bias,
                  float* __restrict__ out) {
  __shared__ __align__(16) unsigned short Ah[64 * 72];
  __shared__ __align__(16) unsigned short Al[64 * 72];
  __shared__ __align__(16) unsigned short Bh[32 * 72];
  __shared__ __align__(16) unsigned short Bl[32 * 72];
  const int n0 = blockIdx.x * 32;  // 0..480
  const int m0 = blockIdx.y * 64;  // 0..960
  const int tid = threadIdx.x;
  const int w = tid >> 6, lane = tid & 63;
  const int quad = lane >> 4, n15 = lane & 15;
  const int srow = tid >> 2;        // 0..63 (A rows)
  const int scol = (tid & 3) * 16;  // 0,16,32,48
  const bool doB = tid >= 128;
  const int brow = (tid & 127) >> 2;   // 0..31 (B rows, waves 2-3)
  const int bcol = (tid & 3) * 16;

  f32x4 acc[2];
#pragma unroll
  for (int nt = 0; nt < 2; ++nt) acc[nt] = (f32x4){0.f, 0.f, 0.f, 0.f};

  uint4 rah0, rah1, ral0, ral1, rbh0, rbh1, rbl0, rbl1;
  {
    const int ar = (m0 + srow) * 512 + scol;
    rah0 = *(const uint4*)&Xah[ar];   rah1 = *(const uint4*)&Xah[ar + 8];
    ral0 = *(const uint4*)&Xal[ar];   ral1 = *(const uint4*)&Xal[ar + 8];
  }
  if (doB) {
    const int br = (n0 + brow) * 512 + bcol;
    rbh0 = *(const uint4*)&Owh[br];   rbh1 = *(const uint4*)&Owh[br + 8];
    rbl0 = *(const uint4*)&Owl[br];   rbl1 = *(const uint4*)&Owl[br + 8];
  }

  for (int k0 = 0; k0 < 512; k0 += 64) {
    __syncthreads();
    *(uint4*)&Ah[srow * 72 + scol] = rah0; *(uint4*)&Ah[srow * 72 + scol + 8] = rah1;
    *(uint4*)&Al[srow * 72 + scol] = ral0; *(uint4*)&Al[srow * 72 + scol + 8] = ral1;
    if (doB) {
      *(uint4*)&Bh[brow * 72 + bcol] = rbh0; *(uint4*)&Bh[brow * 72 + bcol + 8] = rbh1;
      *(uint4*)&Bl[brow * 72 + bcol] = rbl0; *(uint4*)&Bl[brow * 72 + bcol + 8] = rbl1;
    }
    __syncthreads();
    if (k0 + 64 < 512) {
      const int ar = (m0 + srow) * 512 + k0 + 64 + scol;
      rah0 = *(const uint4*)&Xah[ar]; rah1 = *(const uint4*)&Xah[ar + 8];
      ral0 = *(const uint4*)&Xal[ar]; ral1 = *(const uint4*)&Xal[ar + 8];
      if (doB) {
        const int br = (n0 + brow) * 512 + k0 + 64 + bcol;
        rbh0 = *(const uint4*)&Owh[br]; rbh1 = *(const uint4*)&Owh[br + 8];
        rbl0 = *(const uint4*)&Owl[br]; rbl1 = *(const uint4*)&Owl[br + 8];
      }
    }
#pragma unroll
    for (int kk = 0; kk < 2; ++kk) {
      short8 ah = *(const short8*)&Ah[(w * 16 + n15) * 72 + kk * 32 + quad * 8];
      short8 al = *(const short8*)&Al[(w * 16 + n15) * 72 + kk * 32 + quad * 8];
#pragma unroll
      for (int nt = 0; nt < 2; ++nt) {
        short8 bh = *(const short8*)&Bh[(nt * 16 + n15) * 72 + kk * 32 + quad * 8];
        short8 bl = *(const short8*)&Bl[(nt * 16 + n15) * 72 + kk * 32 + quad * 8];
        acc[nt] = __builtin_amdgcn_mfma_f32_16x16x32_bf16(ah, bh, acc[nt], 0, 0, 0);
        acc[nt] = __builtin_amdgcn_mfma_f32_16x16x32_bf16(ah, bl, acc[nt], 0, 0, 0);
        acc[nt] = __builtin_amdgcn_mfma_f32_16x16x32_bf16(al, bh, acc[nt], 0, 0, 0);
      }
    }
  }

#pragma unroll
  for (int nt = 0; nt < 2; ++nt) {
    const int j = n0 + nt * 16 + n15;
    const float bj = bias[j];
#pragma unroll
    for (int r = 0; r < 4; ++r) {
      const int row = m0 + w * 16 + quad * 4 + r;
      out[(size_t)row * 512 + j] = acc[nt][r] + bj;
    }
  }
}

extern "C" void kernel_launch(void* const* d_in, const int* in_sizes, int n_in,
                              void* d_out, int out_size, void* d_ws,
                              size_t ws_size, hipStream_t stream) {
  const float* query = (const float*)d_in[0];
  const float* key   = (const float*)d_in[1];
  const float* value = (const float*)d_in[2];
  const float* cbias = (const float*)d_in[3];
  const float* W     = (const float*)d_in[4];
  const float* pb    = (const float*)d_in[5];
  const float* out_w = (const float*)d_in[6];
  const float* out_b = (const float*)d_in[7];
  float* out = (float*)d_out;

  float* ws = (float*)d_ws;
  float* qh = ws;                                            // 524288 f
  float* kh = ws + 524288;                                   // 524288 f
  unsigned short* vh     = (unsigned short*)(ws + 1048576);  // 524288 us
  unsigned short* attn_h = (unsigned short*)(ws + 1310720);  // 524288 us
  unsigned short* attn_l = (unsigned short*)(ws + 1572864);  // 524288 us
  unsigned short* Xh     = (unsigned short*)(ws + 1835008);  // 1572864 us
  unsigned short* Xl     = (unsigned short*)(ws + 2621440);  // 1572864 us
  unsigned short* Wh     = (unsigned short*)(ws + 3407872);  // 786432 us
  unsigned short* Wl     = (unsigned short*)(ws + 3801088);  // 786432 us
  unsigned short* Owh    = (unsigned short*)(ws + 4194304);  // 262144 us
  unsigned short* Owl    = (unsigned short*)(ws + 4325376);  // 262144 us

  prep_kernel<<<2560, 256, 0, stream>>>(query, key, value, W, out_w,
                                        Xh, Xl, Wh, Wl, Owh, Owl);
  projmm_kernel<<<dim3(48, 16), 256, 0, stream>>>(Xh, Xl, Wh, Wl, pb,
                                                  qh, kh, vh);
  score_kernel<<<1024, 256, 0, stream>>>(qh, kh, vh, cbias, attn_h, attn_l);
  outmm_kernel<<<dim3(16, 16), 256, 0, stream>>>(attn_h, attn_l, Owh, Owl,
                                                 out_b, out);
}

// Round 9
// 178.760 us; speedup vs baseline: 1.0133x; 1.0133x over previous
//
#include <hip/hip_runtime.h>
#include <math.h>

#define SCALING 0.125f

typedef __attribute__((ext_vector_type(8))) short short8;
typedef __attribute__((ext_vector_type(4))) float f32x4;

// round-to-nearest-even fp32 -> bf16
static __device__ __forceinline__ unsigned short bf16r(float x) {
  unsigned int u = __float_as_uint(x);
  u += 0x7fffu + ((u >> 16) & 1u);
  return (unsigned short)(u >> 16);
}
static __device__ __forceinline__ float bf16f(unsigned short h) {
  return __uint_as_float(((unsigned int)h) << 16);
}
// pack two fp32 -> bf16x2 via v_perm_b32 merge
static __device__ __forceinline__ unsigned int pk_bf16(float lo, float hi) {
  unsigned int ua = __float_as_uint(lo);
  unsigned int ub = __float_as_uint(hi);
  ua += 0x7fffu + ((ua >> 16) & 1u);
  ub += 0x7fffu + ((ub >> 16) & 1u);
  return __builtin_amdgcn_perm(ub, ua, 0x07060302u);
}
// fp32x4 -> bf16 hi + residual lo
static __device__ __forceinline__ void split4(float4 x, ushort4& h, ushort4& l) {
  h.x = bf16r(x.x); l.x = bf16r(x.x - bf16f(h.x));
  h.y = bf16r(x.y); l.y = bf16r(x.y - bf16f(h.y));
  h.z = bf16r(x.z); l.z = bf16r(x.z - bf16f(h.z));
  h.w = bf16r(x.w); l.w = bf16r(x.w - bf16f(h.w));
}
union U4S8 { uint4 u; short8 s; };

// async global->LDS, 16B per lane (wave-uniform LDS base + lane*16; per-lane
// global address). Tracked by vmcnt; __syncthreads drains it (m97 semantics).
static __device__ __forceinline__ void gload16(const unsigned short* g,
                                               unsigned short* l) {
  __builtin_amdgcn_global_load_lds(
      (const __attribute__((address_space(1))) void*)(g),
      (__attribute__((address_space(3))) void*)(l), 16, 0, 0);
}

// ---------------------------------------------------------------------------
// Kernel P: one-shot hi/lo bf16 split of all loop-invariant GEMM operands.
// R3-verbatim.
// ---------------------------------------------------------------------------
__global__ __launch_bounds__(256)
void prep_kernel(const float* __restrict__ query,
                 const float* __restrict__ key,
                 const float* __restrict__ value,
                 const float* __restrict__ W,
                 const float* __restrict__ out_w,
                 unsigned short* __restrict__ Xh,
                 unsigned short* __restrict__ Xl,
                 unsigned short* __restrict__ Wh,
                 unsigned short* __restrict__ Wl,
                 unsigned short* __restrict__ Owh,
                 unsigned short* __restrict__ Owl) {
  const int t = blockIdx.x * 256 + threadIdx.x;  // 0..655359
  const int e = t * 4;
  const float* __restrict__ src;
  unsigned short *dh, *dl;
  if (e < 1572864) {               // query|key|value: 3 x 524288 floats
    const int g = e >> 19, j = e & 524287;
    src = (g == 0 ? query : g == 1 ? key : value) + j;
    dh = Xh + e; dl = Xl + e;
  } else if (e < 2359296) {        // W: 1536x512
    const int j = e - 1572864;
    src = W + j; dh = Wh + j; dl = Wl + j;
  } else {                         // out_w: 512x512
    const int j = e - 2359296;
    src = out_w + j; dh = Owh + j; dl = Owl + j;
  }
  const float4 v = *(const float4*)src;
  ushort4 hh, ll;
  split4(v, hh, ll);
  *(ushort4*)dh = hh;
  *(ushort4*)dl = ll;
}

// ---------------------------------------------------------------------------
// GEMM staging template (projmm/outmm): global_load_lds direct-to-LDS with
// double buffer + ONE barrier per K-step (T3-minimum). LDS linear [row][64],
// content XOR-swizzled per rule #21: LDS(row, g) holds global granule
// (row, g^(row&7)); achieved by inverse-swizzling the per-lane GLOBAL
// address (colOff = ((l&7)^(l>>3))*8, stays within the 128B segment ->
// coalescing unchanged) and applying the same XOR on ds_read. Per side:
// Ah[64*64] Al[64*64] Bh[32*64] Bl[32*64] = 12288 us; 2 sides = 49152 B.
// 24 chunks/side (1KB each), 6 per wave. Barriers 16 -> 9; zero staging VALU.
// MFMA order identical to R7 -> bit-identical numerics.
// ---------------------------------------------------------------------------
__global__ __launch_bounds__(256)
void projmm_kernel(const unsigned short* __restrict__ Xh,
                   const unsigned short* __restrict__ Xl,
                   const unsigned short* __restrict__ Wh,
                   const unsigned short* __restrict__ Wl,
                   const float* __restrict__ bias,
                   float* __restrict__ qh, float* __restrict__ kh,
                   unsigned short* __restrict__ vh) {
  __shared__ __align__(16) unsigned short S[2][12288];
  const int n0 = blockIdx.x * 32;  // 0..1504
  const int g = n0 >> 9;           // 0=q,1=k,2=v (32-tiles never straddle 512)
  const unsigned short* __restrict__ Xgh = Xh + g * 524288;
  const unsigned short* __restrict__ Xgl = Xl + g * 524288;
  const int m0 = blockIdx.y * 64;
  const int tid = threadIdx.x;
  const int w = tid >> 6, lane = tid & 63;
  const int quad = lane >> 4, n15 = lane & 15;
  const int lrow = lane >> 3;                       // 0..7 (chunk-local row)
  const int colOff = ((lane & 7) ^ lrow) * 8;       // inverse-swz source col

  // per-wave 6 staging chunks: global base (sans k0) + LDS offset
  const unsigned short* gb[6];
  int lo[6];
#pragma unroll
  for (int j = 0; j < 6; ++j) {
    const int c = w * 6 + j;
    const unsigned short* gsrc;
    int off, grow;
    if (c < 8)       { gsrc = Xgh; off = c * 512;              grow = m0 + c * 8; }
    else if (c < 16) { gsrc = Xgl; off = 4096 + (c - 8) * 512;  grow = m0 + (c - 8) * 8; }
    else if (c < 20) { gsrc = Wh;  off = 8192 + (c - 16) * 512; grow = n0 + (c - 16) * 8; }
    else             { gsrc = Wl;  off = 10240 + (c - 20) * 512; grow = n0 + (c - 20) * 8; }
    gb[j] = gsrc + (size_t)(grow + lrow) * 512 + colOff;
    lo[j] = off;
  }

  f32x4 acc[2];
#pragma unroll
  for (int nt = 0; nt < 2; ++nt) acc[nt] = (f32x4){0.f, 0.f, 0.f, 0.f};

  // prologue: stage k-tile 0 into side 0
#pragma unroll
  for (int j = 0; j < 6; ++j) gload16(gb[j], &S[0][lo[j]]);
  __syncthreads();

  const int rA = w * 16 + n15;
  const int swz = n15 & 7;
  int side = 0;
  for (int k0 = 0; k0 < 512; k0 += 64) {
    if (k0 + 64 < 512) {
      const int ns = side ^ 1;
#pragma unroll
      for (int j = 0; j < 6; ++j) gload16(gb[j] + k0 + 64, &S[ns][lo[j]]);
    }
#pragma unroll
    for (int kk = 0; kk < 2; ++kk) {
      const int gA0 = ((kk * 4 + quad) ^ swz) * 8;
      short8 ah = *(const short8*)&S[side][rA * 64 + gA0];
      short8 al = *(const short8*)&S[side][4096 + rA * 64 + gA0];
#pragma unroll
      for (int nt = 0; nt < 2; ++nt) {
        const int rB = nt * 16 + n15;
        short8 bh = *(const short8*)&S[side][8192 + rB * 64 + gA0];
        short8 bl = *(const short8*)&S[side][10240 + rB * 64 + gA0];
        acc[nt] = __builtin_amdgcn_mfma_f32_16x16x32_bf16(ah, bh, acc[nt], 0, 0, 0);
        acc[nt] = __builtin_amdgcn_mfma_f32_16x16x32_bf16(ah, bl, acc[nt], 0, 0, 0);
        acc[nt] = __builtin_amdgcn_mfma_f32_16x16x32_bf16(al, bh, acc[nt], 0, 0, 0);
      }
    }
    if (k0 + 64 < 512) {
      __syncthreads();  // drains vmcnt (stage done) + all reads of 'side' done
      side ^= 1;
    }
  }

#pragma unroll
  for (int nt = 0; nt < 2; ++nt) {
    const int j = n0 + nt * 16 + n15;
    const int jj = j & 511;
    const int head = jj >> 6;
    const int hd = jj & 63;
    const float bj = bias[j];
#pragma unroll
    for (int r = 0; r < 4; ++r) {
      const int row = m0 + w * 16 + quad * 4 + r;
      const int t = row >> 3;
      const int batch = row & 7;
      const int i = batch * 8 + head;
      const int idx = ((i << 7) + t) * 64 + hd;
      const float val = acc[nt][r] + bj;
      if (g == 0)      qh[idx] = val * SCALING;
      else if (g == 1) kh[idx] = val;
      else             vh[idx] = bf16r(val);
    }
  }
}

// ---------------------------------------------------------------------------
// Kernel B: R8 version (bias as MFMA C-init; measured neutral, fewer insts).
// ---------------------------------------------------------------------------
__global__ __launch_bounds__(256, 2)
void score_kernel(const float* __restrict__ qh,
                  const float* __restrict__ kh,
                  const unsigned short* __restrict__ vh,
                  const float* __restrict__ cbias,
                  unsigned short* __restrict__ attn_h,
                  unsigned short* __restrict__ attn_l) {
  __shared__ __align__(16) unsigned short Ks[2][128 * 72];
  __shared__ __align__(16) unsigned short Vs[2][128 * 72];
  __shared__ float rowS[8 * 128];  // fused rows, then softmax weights

  const int ab = blockIdx.x;  // batch*128 + a
  const int batch = ab >> 7;
  const int a = ab & 127;
  const int tid = threadIdx.x;
  const int w = tid >> 6;
  const int lane = tid & 63;
  const int quad = lane >> 4;
  const int n15 = lane & 15;
  const int col8 = (tid & 7) * 8;

  // bias fragment preload (head-invariant coords; verified mapping)
  const float* __restrict__ bp = cbias + (size_t)ab * 16384;
  f32x4 biasReg[8][2];
#pragma unroll
  for (int ic = 0; ic < 8; ++ic)
#pragma unroll
    for (int jb = 0; jb < 2; ++jb) {
      const int b = w * 32 + jb * 16 + n15;
      biasReg[ic][jb] = *(const f32x4*)&bp[b * 128 + ic * 16 + quad * 4];
    }

  // ---- prologue: stage head 0 into buffer 0 ----
  {
    const int i = batch * 8;
    const float* __restrict__ kb = kh + (size_t)i * 8192;
    const uint4* __restrict__ vb4 = (const uint4*)(vh + (size_t)i * 8192);
    const float* __restrict__ qa = qh + ((size_t)i * 128 + a) * 64;
    f32x4 q0 = *(const f32x4*)&qa[col8];
    f32x4 q1 = *(const f32x4*)&qa[col8 + 4];
#pragma unroll
    for (int j = 0; j < 4; ++j) {
      const int gg = j * 256 + tid;
      const int row = gg >> 3;
      *(uint4*)&Vs[0][row * 72 + col8] = vb4[gg];
      f32x4 k0 = *(const f32x4*)&kb[8 * gg];
      f32x4 k1 = *(const f32x4*)&kb[8 * gg + 4];
      k0 *= q0;
      k1 *= q1;
      uint4 pk;
      pk.x = pk_bf16(k0[0], k0[1]); pk.y = pk_bf16(k0[2], k0[3]);
      pk.z = pk_bf16(k1[0], k1[1]); pk.w = pk_bf16(k1[2], k1[3]);
      *(uint4*)&Ks[0][row * 72 + col8] = pk;
    }
  }
  __syncthreads();

  for (int h = 0; h < 8; ++h) {
    const int buf = h & 1;
    const int i = batch * 8 + h;

    // ---- issue next head's global loads (in flight during MFMA)
    uint4 vreg[4];
    f32x4 kreg[4][2];
    f32x4 qn0, qn1;
    if (h < 7) {
      const int in = i + 1;
      const float* __restrict__ kb = kh + (size_t)in * 8192;
      const uint4* __restrict__ vb4 = (const uint4*)(vh + (size_t)in * 8192);
      const float* __restrict__ qa = qh + ((size_t)in * 128 + a) * 64;
      qn0 = *(const f32x4*)&qa[col8];
      qn1 = *(const f32x4*)&qa[col8 + 4];
#pragma unroll
      for (int j = 0; j < 4; ++j) {
        const int gg = j * 256 + tid;
        vreg[j] = vb4[gg];
        kreg[j][0] = *(const f32x4*)&kb[8 * gg];
        kreg[j][1] = *(const f32x4*)&kb[8 * gg + 4];
      }
    }

    // ---- B-fragments from Ks[buf]
    short8 bf[2][2];
#pragma unroll
    for (int jb = 0; jb < 2; ++jb)
#pragma unroll
      for (int kk = 0; kk < 2; ++kk)
        bf[jb][kk] = *(const short8*)&Ks[buf][(w * 32 + jb * 16 + n15) * 72 +
                                             kk * 32 + quad * 8];

    // ---- MFMA: S^T[c,b]; bias as C-init (R1-verified)
    f32x4 acc[8][2];
#pragma unroll
    for (int ic = 0; ic < 8; ++ic) {
      short8 a0 = *(const short8*)&Vs[buf][(ic * 16 + n15) * 72 + quad * 8];
      short8 a1 = *(const short8*)&Vs[buf][(ic * 16 + n15) * 72 + 32 + quad * 8];
      acc[ic][0] = __builtin_amdgcn_mfma_f32_16x16x32_bf16(a0, bf[0][0], biasReg[ic][0], 0, 0, 0);
      acc[ic][0] = __builtin_amdgcn_mfma_f32_16x16x32_bf16(a1, bf[0][1], acc[ic][0], 0, 0, 0);
      acc[ic][1] = __builtin_amdgcn_mfma_f32_16x16x32_bf16(a0, bf[1][0], biasReg[ic][1], 0, 0, 0);
      acc[ic][1] = __builtin_amdgcn_mfma_f32_16x16x32_bf16(a1, bf[1][1], acc[ic][1], 0, 0, 0);
    }

    // ---- pack + store next head's staging into the other buffer
    if (h < 7) {
      const int nb = buf ^ 1;
#pragma unroll
      for (int j = 0; j < 4; ++j) {
        const int gg = j * 256 + tid;
        const int row = gg >> 3;
        *(uint4*)&Vs[nb][row * 72 + col8] = vreg[j];
        kreg[j][0] *= qn0;
        kreg[j][1] *= qn1;
        uint4 pk;
        pk.x = pk_bf16(kreg[j][0][0], kreg[j][0][1]);
        pk.y = pk_bf16(kreg[j][0][2], kreg[j][0][3]);
        pk.z = pk_bf16(kreg[j][1][0], kreg[j][1][1]);
        pk.w = pk_bf16(kreg[j][1][2], kreg[j][1][3]);
        *(uint4*)&Ks[nb][row * 72 + col8] = pk;
      }
    }

    // ---- epilogue: mean/max over c (bias already in acc) -> rowS (LDS)
    float fsum[2] = {0.f, 0.f};
    float fmx[2] = {-INFINITY, -INFINITY};
#pragma unroll
    for (int ic = 0; ic < 8; ++ic)
#pragma unroll
      for (int jb = 0; jb < 2; ++jb) {
        const float v0 = acc[ic][jb][0];
        const float v1 = acc[ic][jb][1];
        const float v2 = acc[ic][jb][2];
        const float v3 = acc[ic][jb][3];
        fsum[jb] += (v0 + v1) + (v2 + v3);
        fmx[jb] = fmaxf(fmx[jb], fmaxf(fmaxf(v0, v1), fmaxf(v2, v3)));
      }
#pragma unroll
    for (int off = 16; off <= 32; off <<= 1) {
#pragma unroll
      for (int jb = 0; jb < 2; ++jb) {
        fsum[jb] += __shfl_xor(fsum[jb], off, 64);
        fmx[jb] = fmaxf(fmx[jb], __shfl_xor(fmx[jb], off, 64));
      }
    }
    if (quad == 0) {
      rowS[h * 128 + w * 32 + n15] = fsum[0] * (1.0f / 128.0f) + fmx[0];
      rowS[h * 128 + w * 32 + 16 + n15] = fsum[1] * (1.0f / 128.0f) + fmx[1];
    }

    __syncthreads();  // h's reads done; h's stores visible; rowS visible
  }

  // ---- fused tail: softmax over b + attn bmm; wave w handles heads 2w,2w+1
#pragma unroll
  for (int hh = 0; hh < 2; ++hh) {
    const int h = w * 2 + hh;
    const int i = batch * 8 + h;
    float f0 = rowS[h * 128 + lane], f1 = rowS[h * 128 + 64 + lane];
    float m = fmaxf(f0, f1);
#pragma unroll
    for (int off = 32; off >= 1; off >>= 1) m = fmaxf(m, __shfl_xor(m, off, 64));
    const float e0 = expf(f0 - m), e1 = expf(f1 - m);
    float s = e0 + e1;
#pragma unroll
    for (int off = 32; off >= 1; off >>= 1) s += __shfl_xor(s, off, 64);
    const float inv = 1.0f / s;
    rowS[h * 128 + lane] = e0 * inv;       // same wave produces & consumes:
    rowS[h * 128 + 64 + lane] = e1 * inv;  // no barrier needed
    const float* __restrict__ qp = qh + (size_t)i * 8192 + lane;
    float acc2 = 0.0f;
#pragma unroll 8
    for (int b = 0; b < 128; ++b)
      acc2 = fmaf(rowS[h * 128 + b], qp[b * 64], acc2);
    const size_t idx = ((size_t)a * 8 + batch) * 512 + h * 64 + lane;
    const unsigned short hi = bf16r(acc2);
    attn_h[idx] = hi;
    attn_l[idx] = bf16r(acc2 - bf16f(hi));
  }
}

// ---------------------------------------------------------------------------
// Kernel D v6: output projection, same gload_lds single-barrier template.
// ---------------------------------------------------------------------------
__global__ __launch_bounds__(256)
void outmm_kernel(const unsigned short* __restrict__ Xah,
                  const unsigned short* __restrict__ Xal,
                  const unsigned short* __restrict__ Owh,
                  const unsigned short* __restrict__ Owl,
                  const float* __restrict__ bias,
                  float* __restrict__ out) {
  __shared__ __align__(16) unsigned short S[2][12288];
  const int n0 = blockIdx.x * 32;  // 0..480
  const int m0 = blockIdx.y * 64;  // 0..960
  const int tid = threadIdx.x;
  const int w = tid >> 6, lane = tid & 63;
  const int quad = lane >> 4, n15 = lane & 15;
  const int lrow = lane >> 3;
  const int colOff = ((lane & 7) ^ lrow) * 8;

  const unsigned short* gb[6];
  int lo[6];
#pragma unroll
  for (int j = 0; j < 6; ++j) {
    const int c = w * 6 + j;
    const unsigned short* gsrc;
    int off, grow;
    if (c < 8)       { gsrc = Xah; off = c * 512;               grow = m0 + c * 8; }
    else if (c < 16) { gsrc = Xal; off = 4096 + (c - 8) * 512;   grow = m0 + (c - 8) * 8; }
    else if (c < 20) { gsrc = Owh; off = 8192 + (c - 16) * 512;  grow = n0 + (c - 16) * 8; }
    else             { gsrc = Owl; off = 10240 + (c - 20) * 512; grow = n0 + (c - 20) * 8; }
    gb[j] = gsrc + (size_t)(grow + lrow) * 512 + colOff;
    lo[j] = off;
  }

  f32x4 acc[2];
#pragma unroll
  for (int nt = 0; nt < 2; ++nt) acc[nt] = (f32x4){0.f, 0.f, 0.f, 0.f};

#pragma unroll
  for (int j = 0; j < 6; ++j) gload16(gb[j], &S[0][lo[j]]);
  __syncthreads();

  const int rA = w * 16 + n15;
  const int swz = n15 & 7;
  int side = 0;
  for (int k0 = 0; k0 < 512; k0 += 64) {
    if (k0 + 64 < 512) {
      const int ns = side ^ 1;
#pragma unroll
      for (int j = 0; j < 6; ++j) gload16(gb[j] + k0 + 64, &S[ns][lo[j]]);
    }
#pragma unroll
    for (int kk = 0; kk < 2; ++kk) {
      const int gA0 = ((kk * 4 + quad) ^ swz) * 8;
      short8 ah = *(const short8*)&S[side][rA * 64 + gA0];
      short8 al = *(const short8*)&S[side][4096 + rA * 64 + gA0];
#pragma unroll
      for (int nt = 0; nt < 2; ++nt) {
        const int rB = nt * 16 + n15;
        short8 bh = *(const short8*)&S[side][8192 + rB * 64 + gA0];
        short8 bl = *(const short8*)&S[side][10240 + rB * 64 + gA0];
        acc[nt] = __builtin_amdgcn_mfma_f32_16x16x32_bf16(ah, bh, acc[nt], 0, 0, 0);
        acc[nt] = __builtin_amdgcn_mfma_f32_16x16x32_bf16(ah, bl, acc[nt], 0, 0, 0);
        acc[nt] = __builtin_amdgcn_mfma_f32_16x16x32_bf16(al, bh, acc[nt], 0, 0, 0);
      }
    }
    if (k0 + 64 < 512) {
      __syncthreads();
      side ^= 1;
    }
  }

#pragma unroll
  for (int nt = 0; nt < 2; ++nt) {
    const int j = n0 + nt * 16 + n15;
    const float bj = bias[j];
#pragma unroll
    for (int r = 0; r < 4; ++r) {
      const int row = m0 + w * 16 + quad * 4 + r;
      out[(size_t)row * 512 + j] = acc[nt][r] + bj;
    }
  }
}

extern "C" void kernel_launch(void* const* d_in, const int* in_sizes, int n_in,
                              void* d_out, int out_size, void* d_ws,
                              size_t ws_size, hipStream_t stream) {
  const float* query = (const float*)d_in[0];
  const float* key   = (const float*)d_in[1];
  const float* value = (const float*)d_in[2];
  const float* cbias = (const float*)d_in[3];
  const float* W     = (const float*)d_in[4];
  const float* pb    = (const float*)d_in[5];
  const float* out_w = (const float*)d_in[6];
  const float* out_b = (const float*)d_in[7];
  float* out = (float*)d_out;

  float* ws = (float*)d_ws;
  float* qh = ws;                                            // 524288 f
  float* kh = ws + 524288;                                   // 524288 f
  unsigned short* vh     = (unsigned short*)(ws + 1048576);  // 524288 us
  unsigned short* attn_h = (unsigned short*)(ws + 1310720);  // 524288 us
  unsigned short* attn_l = (unsigned short*)(ws + 1572864);  // 524288 us
  unsigned short* Xh     = (unsigned short*)(ws + 1835008);  // 1572864 us
  unsigned short* Xl     = (unsigned short*)(ws + 2621440);  // 1572864 us
  unsigned short* Wh     = (unsigned short*)(ws + 3407872);  // 786432 us
  unsigned short* Wl     = (unsigned short*)(ws + 3801088);  // 786432 us
  unsigned short* Owh    = (unsigned short*)(ws + 4194304);  // 262144 us
  unsigned short* Owl    = (unsigned short*)(ws + 4325376);  // 262144 us

  prep_kernel<<<2560, 256, 0, stream>>>(query, key, value, W, out_w,
                                        Xh, Xl, Wh, Wl, Owh, Owl);
  projmm_kernel<<<dim3(48, 16), 256, 0, stream>>>(Xh, Xl, Wh, Wl, pb,
                                                  qh, kh, vh);
  score_kernel<<<1024, 256, 0, stream>>>(qh, kh, vh, cbias, attn_h, attn_l);
  outmm_kernel<<<dim3(16, 16), 256, 0, stream>>>(attn_h, attn_l, Owh, Owl,
                                                 out_b, out);
}